// Round 19
// baseline (48.281 us; speedup 1.0000x reference)
//
#include <hip/hip_runtime.h>
#include <hip/hip_bf16.h>

typedef __attribute__((ext_vector_type(4))) int i32x4;

constexpr int NB = 8, CI = 256, OC = 256, HH = 64, WW = 64, HP = 66, WP = 66;
constexpr int NBASES = 5;
constexpr int WELEMS = OC * CI * 9;      // 589824 per basis
constexpr int NT = 36;                   // 9 taps x 4 chunks of 64 channels
constexpr int ABS_CHUNK = 8192;          // elems per abs block; 72 blocks/basis
constexpr int SIGN_BYTES = WELEMS / 8;   // 73728 per basis
constexpr int ABS_BLOCKS = NBASES * 72;  // 360

// ---- 1) fused: blocks [0,360) = per-basis |w| partials + sign bitmap;
//              blocks [360,872) = quantize x to i8 NHWC-padded.
//      The two branches are independent -> run concurrently in one launch. ----
__global__ void k_main1(const float* __restrict__ w, float* __restrict__ part,
                        unsigned char* __restrict__ signs,
                        const float* __restrict__ x, signed char* __restrict__ xq) {
    int tid = threadIdx.x;

    if (blockIdx.x < ABS_BLOCKS) {
        int b = blockIdx.x / 72, chunk = blockIdx.x % 72;
        const float* wb = w + (size_t)b * WELEMS + chunk * ABS_CHUNK;
        unsigned char* sb = signs + (size_t)b * SIGN_BYTES + chunk * (ABS_CHUNK / 8);
        float s = 0.f;
        #pragma unroll
        for (int j = 0; j < 4; ++j) {
            int byteIdx = tid + j * 256;               // 0..1023
            float4 v0 = *(const float4*)(wb + byteIdx * 8);
            float4 v1 = *(const float4*)(wb + byteIdx * 8 + 4);
            s += fabsf(v0.x) + fabsf(v0.y) + fabsf(v0.z) + fabsf(v0.w)
               + fabsf(v1.x) + fabsf(v1.y) + fabsf(v1.z) + fabsf(v1.w);
            unsigned m = 0;
            m |= (v0.x < 0.f) ? 1u   : 0u;  m |= (v0.y < 0.f) ? 2u   : 0u;
            m |= (v0.z < 0.f) ? 4u   : 0u;  m |= (v0.w < 0.f) ? 8u   : 0u;
            m |= (v1.x < 0.f) ? 16u  : 0u;  m |= (v1.y < 0.f) ? 32u  : 0u;
            m |= (v1.z < 0.f) ? 64u  : 0u;  m |= (v1.w < 0.f) ? 128u : 0u;
            sb[byteIdx] = (unsigned char)m;
        }
        #pragma unroll
        for (int off = 32; off; off >>= 1) s += __shfl_down(s, off, 64);
        __shared__ float ls[4];
        int lane = tid & 63, wid = tid >> 6;
        if (lane == 0) ls[wid] = s;
        __syncthreads();
        if (tid == 0) part[blockIdx.x] = ls[0] + ls[1] + ls[2] + ls[3];
        return;
    }

    // ---- xq_pad[n][h+1][w+1][c] = i8(round(clip(x,0,1))), borders 0 ----
    int nh = blockIdx.x - ABS_BLOCKS, n = nh >> 6, h = nh & 63;
    const float* xb = x + ((size_t)n * CI) * (HH * WW) + h * WW;   // + c*4096 + w
    signed char* ob = xq + ((size_t)(n * HP + (h + 1)) * WP + 1) * CI;
    int w4 = tid >> 2;             // 0..63
    int cl = tid & 3;              // 0..3
    #pragma unroll
    for (int p = 0; p < 4; ++p) {
        int c = (p * 4 + cl) * 16;
        signed char pk[16];
        #pragma unroll
        for (int i = 0; i < 16; ++i) {
            float v = xb[(size_t)(c + i) * (HH * WW) + w4];
            pk[i] = (signed char)rintf(fminf(fmaxf(v, 0.f), 1.f));
        }
        *(int4*)(ob + w4 * CI + c) = *(const int4*)pk;
    }
    (ob - CI)[tid] = 0;
    (ob + 64 * CI)[tid] = 0;
    if (h == 0) {
        signed char* r0 = xq + ((size_t)(n * HP + 0) * WP) * CI;
        int4 z = {0, 0, 0, 0};
        for (int i = tid; i < WP * CI / 16; i += 256) *(int4*)(r0 + i * 16) = z;
    }
    if (h == HH - 1) {
        signed char* r65 = xq + ((size_t)(n * HP + (HP - 1)) * WP) * CI;
        int4 z = {0, 0, 0, 0};
        for (int i = tid; i < WP * CI / 16; i += 256) *(int4*)(r65 + i * 16) = z;
    }
}

// ---- 2) wsum8 from sign bitmap + LUT : grid 256 (one block per oc), ~1.5 us ----
__global__ void k_wsum(const unsigned char* __restrict__ signs,
                       const float* __restrict__ part,
                       signed char* __restrict__ wsum8, float* __restrict__ scl) {
    __shared__ float sLDS[NBASES];
    __shared__ float lutq[32];             // lut[mask] = (sum_b ±s_b) * 127/sSum
    int tid = threadIdx.x;

    if (tid < 64) {
        #pragma unroll
        for (int b = 0; b < NBASES; ++b) {
            float v = part[b * 72 + tid] + (tid < 8 ? part[b * 72 + 64 + tid] : 0.f);
            #pragma unroll
            for (int off = 32; off; off >>= 1) v += __shfl_down(v, off, 64);
            if (tid == 0) sLDS[b] = v * (1.0f / (float)WELEMS);
        }
    }
    __syncthreads();
    float sc[NBASES];
    #pragma unroll
    for (int b = 0; b < NBASES; ++b) sc[b] = sLDS[b];
    float sSum = sc[0] + sc[1] + sc[2] + sc[3] + sc[4];
    float invS = 127.0f / sSum;
    if (blockIdx.x == 0 && tid == 0)
        scl[0] = sSum * (0.2f / 127.0f);        // out scale = (sSum/5)/127
    if (tid < 32) {
        float a = 0.f;
        #pragma unroll
        for (int b = 0; b < NBASES; ++b)
            a += ((tid >> b) & 1) ? -sc[b] : sc[b];   // bit=1 <=> negative weight
        lutq[tid] = a * invS;
    }
    __syncthreads();

    int o = blockIdx.x, i = tid;
    int e0 = (o * CI + i) * 9;                 // bit index of tap 0
    int bytePos = e0 >> 3, shift = e0 & 7;
    unsigned bits[NBASES];
    #pragma unroll
    for (int b = 0; b < NBASES; ++b) {
        const unsigned char* sb = signs + (size_t)b * SIGN_BYTES + bytePos;
        unsigned v = (unsigned)sb[0] | ((unsigned)sb[1] << 8);
        bits[b] = (v >> shift) & 0x1FFu;       // 9 sign bits, tap-major
    }
    #pragma unroll
    for (int t = 0; t < 9; ++t) {
        unsigned mask = 0;
        #pragma unroll
        for (int b = 0; b < NBASES; ++b)
            mask |= ((bits[b] >> t) & 1u) << b;
        wsum8[(t * OC + o) * CI + i] = (signed char)__float2int_rn(lutq[mask]);
    }
}

// ---- 3) conv i8 (best measured, unchanged): 128x128 tile, BK=64B, 4 waves,
//      4-buf LDS, 2 blocks/CU, one-step register read-ahead, counted vmcnt(4). ----
__launch_bounds__(256, 2)
__global__ void k_conv(const signed char* __restrict__ xq,
                       const signed char* __restrict__ wsum,
                       const float* __restrict__ scl,
                       float* __restrict__ out) {
    __shared__ __align__(16) signed char lA[4][128 * 64];  // 4 x 8 KB
    __shared__ __align__(16) signed char lB[4][128 * 64];  // 4 x 8 KB

    float so = scl[0];

    // XCD-chunked swizzle: 512 blocks, 64 logical per XCD (= 1 image x both oc halves)
    int bid = blockIdx.x;
    int bx = ((bid & 7) << 6) | (bid >> 3);
    int pt = bx >> 1, ot = bx & 1;
    int pb = pt * 128;                 // first pixel (n*4096 + h*64 + w); 2 h-rows
    int n = pb >> 12;
    int h0 = (pb >> 6) & 63;
    int oc0 = ot * 128;
    int tid = threadIdx.x;

    int base0 = (n * HP + h0) * WP * CI;   // byte offset (CI bytes per pixel)
    int bBase0 = oc0 * CI;

    // staging: 512 chunks of 16B per tile; chunk c: row=c>>2, sp=c&3,
    // fetch logical k-slot l = sp ^ ((row>>1)&3)  (linear LDS dest, swizzled source)
    int aOff[2], bOff[2];
    #pragma unroll
    for (int k = 0; k < 2; ++k) {
        int c = tid + k * 256;
        int row = c >> 2, sp = c & 3;
        int l = sp ^ ((row >> 1) & 3);
        aOff[k] = ((row >> 6) * WP + (row & 63)) * CI + l * 16;
        bOff[k] = row * CI + l * 16;
    }

    int lane = tid & 63, wid = tid >> 6;
    int wm = wid >> 1, wn = wid & 1;        // 2M x 2N waves, 64x64 per wave
    int g = lane >> 4, r16 = lane & 15;
    // frag byte offsets: row r, logical slot g lives at physical g ^ ((r>>1)&3)
    int fA[4], fB[4];
    #pragma unroll
    for (int q = 0; q < 4; ++q) {
        int ra = wm * 64 + q * 16 + r16;
        fA[q] = ra * 64 + (g ^ ((ra >> 1) & 3)) * 16;
        int rb = wn * 64 + q * 16 + r16;
        fB[q] = rb * 64 + (g ^ ((rb >> 1) & 3)) * 16;
    }

    i32x4 acc[4][4] = {};

    auto stage = [&](int t) {
        int buf = t & 3;
        int tap = t >> 2;
        int c0 = (t & 3) << 6;             // 64-byte channel chunk
        int kh = (tap * 171) >> 9;         // tap/3
        int kw = tap - kh * 3;
        const signed char* aSrc = xq + base0 + (kh * WP + kw) * CI + c0;
        const signed char* bSrc = wsum + tap * (OC * CI) + bBase0 + c0;
        #pragma unroll
        for (int k = 0; k < 2; ++k) {
            __builtin_amdgcn_global_load_lds(
                (const __attribute__((address_space(1))) void*)(aSrc + aOff[k]),
                (__attribute__((address_space(3))) void*)(&lA[buf][(tid + k * 256) * 16]), 16, 0, 0);
            __builtin_amdgcn_global_load_lds(
                (const __attribute__((address_space(1))) void*)(bSrc + bOff[k]),
                (__attribute__((address_space(3))) void*)(&lB[buf][(tid + k * 256) * 16]), 16, 0, 0);
        }
    };
    auto readFrags = [&](int buf, i32x4 (&aR)[4], i32x4 (&bR)[4]) {
        #pragma unroll
        for (int q = 0; q < 4; ++q) aR[q] = *(const i32x4*)&lA[buf][fA[q]];
        #pragma unroll
        for (int q = 0; q < 4; ++q) bR[q] = *(const i32x4*)&lB[buf][fB[q]];
    };
    auto mfmaCluster = [&](i32x4 (&aR)[4], i32x4 (&bR)[4]) {
        __builtin_amdgcn_s_setprio(1);
        #pragma unroll
        for (int mq = 0; mq < 4; ++mq)
            #pragma unroll
            for (int nq = 0; nq < 4; ++nq)
                acc[mq][nq] = __builtin_amdgcn_mfma_i32_16x16x64_i8(
                    aR[mq], bR[nq], acc[mq][nq], 0, 0, 0);
        __builtin_amdgcn_s_setprio(0);
    };

    // prologue: 3 K-steps staged; frags for step 0 in regs (set0)
    stage(0); stage(1); stage(2);
    asm volatile("s_waitcnt vmcnt(8)" ::: "memory");   // buf0 complete
    __builtin_amdgcn_s_barrier();
    i32x4 a0[4], b0[4], a1[4], b1[4];
    readFrags(0, a0, b0);

    // invariant at step-t top: frags t in regs; stages issued through t+2;
    // stages <= t complete. Step: ensure buf[t+1] done (vmcnt(4): only t+2
    // in flight), barrier, stage(t+3) [overwrites buf[(t-1)&3]], issue frag
    // reads for t+1, MFMA frags t. Manual 2x unroll keeps reg sets static.
    #pragma unroll 1
    for (int p = 0; p < NT / 2; ++p) {
        int t = 2 * p;
        {   // even step: cur=set0, next=set1
            if (t + 2 <= NT - 1) asm volatile("s_waitcnt vmcnt(4)" ::: "memory");
            else                 asm volatile("s_waitcnt vmcnt(0)" ::: "memory");
            __builtin_amdgcn_s_barrier();
            __builtin_amdgcn_sched_barrier(0);
            if (t + 3 < NT) stage(t + 3);
            readFrags((t + 1) & 3, a1, b1);
            __builtin_amdgcn_sched_barrier(0);   // keep reads above the MFMAs
            mfmaCluster(a0, b0);
        }
        t = 2 * p + 1;
        {   // odd step: cur=set1, next=set0
            if (t < NT - 1) {
                if (t + 2 <= NT - 1) asm volatile("s_waitcnt vmcnt(4)" ::: "memory");
                else                 asm volatile("s_waitcnt vmcnt(0)" ::: "memory");
                __builtin_amdgcn_s_barrier();
                __builtin_amdgcn_sched_barrier(0);
                if (t + 3 < NT) stage(t + 3);
                readFrags((t + 1) & 3, a0, b0);
                __builtin_amdgcn_sched_barrier(0);
            }
            mfmaCluster(a1, b1);
        }
    }

    // epilogue: C/D 16x16: col=lane&15 (oc), row=(lane>>4)*4+reg (pixel); scale to fp32
    int hw0 = pb & 4095;
    #pragma unroll
    for (int mq = 0; mq < 4; ++mq) {
        int pl = wm * 64 + mq * 16 + g * 4;
        #pragma unroll
        for (int nq = 0; nq < 4; ++nq) {
            int oc = oc0 + wn * 64 + nq * 16 + r16;
            float4 v;
            v.x = (float)acc[mq][nq][0] * so;
            v.y = (float)acc[mq][nq][1] * so;
            v.z = (float)acc[mq][nq][2] * so;
            v.w = (float)acc[mq][nq][3] * so;
            *(float4*)(out + ((size_t)(n * OC + oc) << 12) + hw0 + pl) = v;
        }
    }
}

extern "C" void kernel_launch(void* const* d_in, const int* in_sizes, int n_in,
                              void* d_out, int out_size, void* d_ws, size_t ws_size,
                              hipStream_t stream) {
    (void)in_sizes; (void)n_in; (void)out_size; (void)ws_size;
    const float* x   = (const float*)d_in[0];
    const float* wts = (const float*)d_in[1];
    float* out = (float*)d_out;
    char* wsb = (char*)d_ws;
    float* part          = (float*)wsb;                        // 360 floats
    float* scl           = (float*)(wsb + 2048);               // 1 float
    signed char* wsum8   = (signed char*)(wsb + 4096);         // 576 KB
    unsigned char* signs = (unsigned char*)(wsb + (size_t)(1u << 20)); // 360 KB bitmap
    signed char* xq8     = (signed char*)(wsb + (size_t)(2u << 20));   // ~8.9 MB

    hipLaunchKernelGGL(k_main1, dim3(ABS_BLOCKS + NB * HH), dim3(256), 0, stream,
                       wts, part, signs, x, xq8);
    hipLaunchKernelGGL(k_wsum, dim3(OC), dim3(256), 0, stream,
                       signs, part, wsum8, scl);
    hipLaunchKernelGGL(k_conv, dim3((NB * HH * WW / 128) * (OC / 128)), dim3(256), 0, stream,
                       xq8, wsum8, scl, out);
}

// Round 20
// 47.404 us; speedup vs baseline: 1.0185x; 1.0185x over previous
//
#include <hip/hip_runtime.h>
#include <hip/hip_bf16.h>

typedef __attribute__((ext_vector_type(4))) int i32x4;

constexpr int NB = 8, CI = 256, OC = 256, HH = 64, WW = 64, HP = 66, WP = 66;
constexpr int NBASES = 5;
constexpr int WELEMS = OC * CI * 9;      // 589824 per basis
constexpr int NT = 36;                   // 9 taps x 4 chunks of 64 channels
constexpr int ABS_CHUNK = 8192;          // elems per abs block; 72 blocks/basis
constexpr int SIGN_BYTES = WELEMS / 8;   // 73728 per basis

// ---- 1) per-basis partial |w| sums + packed sign bitmap : grid 5*72, block 256 ----
__global__ void k_abs_partial(const float* __restrict__ w, float* __restrict__ part,
                              unsigned char* __restrict__ signs) {
    int b = blockIdx.x / 72, chunk = blockIdx.x % 72;
    const float* wb = w + (size_t)b * WELEMS + chunk * ABS_CHUNK;
    unsigned char* sb = signs + (size_t)b * SIGN_BYTES + chunk * (ABS_CHUNK / 8);
    float s = 0.f;
    #pragma unroll
    for (int j = 0; j < 4; ++j) {
        int byteIdx = threadIdx.x + j * 256;           // 0..1023
        float4 v0 = *(const float4*)(wb + byteIdx * 8);
        float4 v1 = *(const float4*)(wb + byteIdx * 8 + 4);
        s += fabsf(v0.x) + fabsf(v0.y) + fabsf(v0.z) + fabsf(v0.w)
           + fabsf(v1.x) + fabsf(v1.y) + fabsf(v1.z) + fabsf(v1.w);
        unsigned m = 0;
        m |= (v0.x < 0.f) ? 1u   : 0u;  m |= (v0.y < 0.f) ? 2u   : 0u;
        m |= (v0.z < 0.f) ? 4u   : 0u;  m |= (v0.w < 0.f) ? 8u   : 0u;
        m |= (v1.x < 0.f) ? 16u  : 0u;  m |= (v1.y < 0.f) ? 32u  : 0u;
        m |= (v1.z < 0.f) ? 64u  : 0u;  m |= (v1.w < 0.f) ? 128u : 0u;
        sb[byteIdx] = (unsigned char)m;
    }
    #pragma unroll
    for (int off = 32; off; off >>= 1) s += __shfl_down(s, off, 64);
    __shared__ float ls[4];
    int lane = threadIdx.x & 63, wid = threadIdx.x >> 6;
    if (lane == 0) ls[wid] = s;
    __syncthreads();
    if (threadIdx.x == 0) part[blockIdx.x] = ls[0] + ls[1] + ls[2] + ls[3];
}

// ---- 2) fused prep (i8): blocks [0,256) build wsum8 from SIGN BITMAP + LUT;
//         blocks [256,768) quantize x (proven load/store pattern) ----
__global__ void k_prep(const unsigned char* __restrict__ signs,
                       const float* __restrict__ part,
                       signed char* __restrict__ wsum8, float* __restrict__ scl,
                       const float* __restrict__ x, signed char* __restrict__ xq) {
    __shared__ float sLDS[NBASES];
    __shared__ float lutq[32];             // lut[mask] = (sum_b ±s_b) * 127/sSum
    int tid = threadIdx.x;

    if (blockIdx.x < OC) {
        if (tid < 64) {
            #pragma unroll
            for (int b = 0; b < NBASES; ++b) {
                float v = part[b * 72 + tid] + (tid < 8 ? part[b * 72 + 64 + tid] : 0.f);
                #pragma unroll
                for (int off = 32; off; off >>= 1) v += __shfl_down(v, off, 64);
                if (tid == 0) sLDS[b] = v * (1.0f / (float)WELEMS);
            }
        }
        __syncthreads();
        float sc[NBASES];
        #pragma unroll
        for (int b = 0; b < NBASES; ++b) sc[b] = sLDS[b];
        float sSum = sc[0] + sc[1] + sc[2] + sc[3] + sc[4];
        float invS = 127.0f / sSum;
        if (blockIdx.x == 0 && tid == 0)
            scl[0] = sSum * (0.2f / 127.0f);        // out scale = (sSum/5)/127
        if (tid < 32) {
            float a = 0.f;
            #pragma unroll
            for (int b = 0; b < NBASES; ++b)
                a += ((tid >> b) & 1) ? -sc[b] : sc[b];   // bit=1 <=> negative weight
            lutq[tid] = a * invS;
        }
        __syncthreads();

        int o = blockIdx.x, i = tid;
        int e0 = (o * CI + i) * 9;                 // bit index of tap 0
        int bytePos = e0 >> 3, shift = e0 & 7;
        unsigned bits[NBASES];
        #pragma unroll
        for (int b = 0; b < NBASES; ++b) {
            const unsigned char* sb = signs + (size_t)b * SIGN_BYTES + bytePos;
            unsigned v = (unsigned)sb[0] | ((unsigned)sb[1] << 8);
            bits[b] = (v >> shift) & 0x1FFu;       // 9 sign bits, tap-major
        }
        #pragma unroll
        for (int t = 0; t < 9; ++t) {
            unsigned mask = 0;
            #pragma unroll
            for (int b = 0; b < NBASES; ++b)
                mask |= ((bits[b] >> t) & 1u) << b;
            wsum8[(t * OC + o) * CI + i] = (signed char)__float2int_rn(lutq[mask]);
        }
        return;
    }

    // ---- xq_pad[n][h+1][w+1][c] = i8(round(clip(x,0,1))), borders 0 ----
    int nh = blockIdx.x - OC, n = nh >> 6, h = nh & 63;
    const float* xb = x + ((size_t)n * CI) * (HH * WW) + h * WW;   // + c*4096 + w
    signed char* ob = xq + ((size_t)(n * HP + (h + 1)) * WP + 1) * CI;
    int w4 = tid >> 2;             // 0..63
    int cl = tid & 3;              // 0..3
    #pragma unroll
    for (int p = 0; p < 4; ++p) {
        int c = (p * 4 + cl) * 16;
        signed char pk[16];
        #pragma unroll
        for (int i = 0; i < 16; ++i) {
            float v = xb[(size_t)(c + i) * (HH * WW) + w4];
            pk[i] = (signed char)rintf(fminf(fmaxf(v, 0.f), 1.f));
        }
        *(int4*)(ob + w4 * CI + c) = *(const int4*)pk;
    }
    (ob - CI)[tid] = 0;
    (ob + 64 * CI)[tid] = 0;
    if (h == 0) {
        signed char* r0 = xq + ((size_t)(n * HP + 0) * WP) * CI;
        int4 z = {0, 0, 0, 0};
        for (int i = tid; i < WP * CI / 16; i += 256) *(int4*)(r0 + i * 16) = z;
    }
    if (h == HH - 1) {
        signed char* r65 = xq + ((size_t)(n * HP + (HP - 1)) * WP) * CI;
        int4 z = {0, 0, 0, 0};
        for (int i = tid; i < WP * CI / 16; i += 256) *(int4*)(r65 + i * 16) = z;
    }
}

// ---- 3) conv i8 (best measured): 128x128 tile, BK=64B, 4 waves, 4-buf LDS,
//      2 blocks/CU, one-step register read-ahead, counted vmcnt(4).
//      At the LDS-port roofline for this structure: 1030 cy budget vs
//      1050 cy measured per CU-window. ----
__launch_bounds__(256, 2)
__global__ void k_conv(const signed char* __restrict__ xq,
                       const signed char* __restrict__ wsum,
                       const float* __restrict__ scl,
                       float* __restrict__ out) {
    __shared__ __align__(16) signed char lA[4][128 * 64];  // 4 x 8 KB
    __shared__ __align__(16) signed char lB[4][128 * 64];  // 4 x 8 KB

    float so = scl[0];

    // XCD-chunked swizzle: 512 blocks, 64 logical per XCD (= 1 image x both oc halves)
    int bid = blockIdx.x;
    int bx = ((bid & 7) << 6) | (bid >> 3);
    int pt = bx >> 1, ot = bx & 1;
    int pb = pt * 128;                 // first pixel (n*4096 + h*64 + w); 2 h-rows
    int n = pb >> 12;
    int h0 = (pb >> 6) & 63;
    int oc0 = ot * 128;
    int tid = threadIdx.x;

    int base0 = (n * HP + h0) * WP * CI;   // byte offset (CI bytes per pixel)
    int bBase0 = oc0 * CI;

    // staging: 512 chunks of 16B per tile; chunk c: row=c>>2, sp=c&3,
    // fetch logical k-slot l = sp ^ ((row>>1)&3)  (linear LDS dest, swizzled source)
    int aOff[2], bOff[2];
    #pragma unroll
    for (int k = 0; k < 2; ++k) {
        int c = tid + k * 256;
        int row = c >> 2, sp = c & 3;
        int l = sp ^ ((row >> 1) & 3);
        aOff[k] = ((row >> 6) * WP + (row & 63)) * CI + l * 16;
        bOff[k] = row * CI + l * 16;
    }

    int lane = tid & 63, wid = tid >> 6;
    int wm = wid >> 1, wn = wid & 1;        // 2M x 2N waves, 64x64 per wave
    int g = lane >> 4, r16 = lane & 15;
    // frag byte offsets: row r, logical slot g lives at physical g ^ ((r>>1)&3)
    int fA[4], fB[4];
    #pragma unroll
    for (int q = 0; q < 4; ++q) {
        int ra = wm * 64 + q * 16 + r16;
        fA[q] = ra * 64 + (g ^ ((ra >> 1) & 3)) * 16;
        int rb = wn * 64 + q * 16 + r16;
        fB[q] = rb * 64 + (g ^ ((rb >> 1) & 3)) * 16;
    }

    i32x4 acc[4][4] = {};

    auto stage = [&](int t) {
        int buf = t & 3;
        int tap = t >> 2;
        int c0 = (t & 3) << 6;             // 64-byte channel chunk
        int kh = (tap * 171) >> 9;         // tap/3
        int kw = tap - kh * 3;
        const signed char* aSrc = xq + base0 + (kh * WP + kw) * CI + c0;
        const signed char* bSrc = wsum + tap * (OC * CI) + bBase0 + c0;
        #pragma unroll
        for (int k = 0; k < 2; ++k) {
            __builtin_amdgcn_global_load_lds(
                (const __attribute__((address_space(1))) void*)(aSrc + aOff[k]),
                (__attribute__((address_space(3))) void*)(&lA[buf][(tid + k * 256) * 16]), 16, 0, 0);
            __builtin_amdgcn_global_load_lds(
                (const __attribute__((address_space(1))) void*)(bSrc + bOff[k]),
                (__attribute__((address_space(3))) void*)(&lB[buf][(tid + k * 256) * 16]), 16, 0, 0);
        }
    };
    auto readFrags = [&](int buf, i32x4 (&aR)[4], i32x4 (&bR)[4]) {
        #pragma unroll
        for (int q = 0; q < 4; ++q) aR[q] = *(const i32x4*)&lA[buf][fA[q]];
        #pragma unroll
        for (int q = 0; q < 4; ++q) bR[q] = *(const i32x4*)&lB[buf][fB[q]];
    };
    auto mfmaCluster = [&](i32x4 (&aR)[4], i32x4 (&bR)[4]) {
        __builtin_amdgcn_s_setprio(1);
        #pragma unroll
        for (int mq = 0; mq < 4; ++mq)
            #pragma unroll
            for (int nq = 0; nq < 4; ++nq)
                acc[mq][nq] = __builtin_amdgcn_mfma_i32_16x16x64_i8(
                    aR[mq], bR[nq], acc[mq][nq], 0, 0, 0);
        __builtin_amdgcn_s_setprio(0);
    };

    // prologue: 3 K-steps staged; frags for step 0 in regs (set0)
    stage(0); stage(1); stage(2);
    asm volatile("s_waitcnt vmcnt(8)" ::: "memory");   // buf0 complete
    __builtin_amdgcn_s_barrier();
    i32x4 a0[4], b0[4], a1[4], b1[4];
    readFrags(0, a0, b0);

    // invariant at step-t top: frags t in regs; stages issued through t+2;
    // stages <= t complete. Step: ensure buf[t+1] done (vmcnt(4): only t+2
    // in flight), barrier, stage(t+3) [overwrites buf[(t-1)&3]], issue frag
    // reads for t+1, MFMA frags t. Manual 2x unroll keeps reg sets static.
    #pragma unroll 1
    for (int p = 0; p < NT / 2; ++p) {
        int t = 2 * p;
        {   // even step: cur=set0, next=set1
            if (t + 2 <= NT - 1) asm volatile("s_waitcnt vmcnt(4)" ::: "memory");
            else                 asm volatile("s_waitcnt vmcnt(0)" ::: "memory");
            __builtin_amdgcn_s_barrier();
            __builtin_amdgcn_sched_barrier(0);
            if (t + 3 < NT) stage(t + 3);
            readFrags((t + 1) & 3, a1, b1);
            __builtin_amdgcn_sched_barrier(0);   // keep reads above the MFMAs
            mfmaCluster(a0, b0);
        }
        t = 2 * p + 1;
        {   // odd step: cur=set1, next=set0
            if (t < NT - 1) {
                if (t + 2 <= NT - 1) asm volatile("s_waitcnt vmcnt(4)" ::: "memory");
                else                 asm volatile("s_waitcnt vmcnt(0)" ::: "memory");
                __builtin_amdgcn_s_barrier();
                __builtin_amdgcn_sched_barrier(0);
                if (t + 3 < NT) stage(t + 3);
                readFrags((t + 1) & 3, a0, b0);
                __builtin_amdgcn_sched_barrier(0);
            }
            mfmaCluster(a1, b1);
        }
    }

    // epilogue: C/D 16x16: col=lane&15 (oc), row=(lane>>4)*4+reg (pixel); scale to fp32
    int hw0 = pb & 4095;
    #pragma unroll
    for (int mq = 0; mq < 4; ++mq) {
        int pl = wm * 64 + mq * 16 + g * 4;
        #pragma unroll
        for (int nq = 0; nq < 4; ++nq) {
            int oc = oc0 + wn * 64 + nq * 16 + r16;
            float4 v;
            v.x = (float)acc[mq][nq][0] * so;
            v.y = (float)acc[mq][nq][1] * so;
            v.z = (float)acc[mq][nq][2] * so;
            v.w = (float)acc[mq][nq][3] * so;
            *(float4*)(out + ((size_t)(n * OC + oc) << 12) + hw0 + pl) = v;
        }
    }
}

extern "C" void kernel_launch(void* const* d_in, const int* in_sizes, int n_in,
                              void* d_out, int out_size, void* d_ws, size_t ws_size,
                              hipStream_t stream) {
    (void)in_sizes; (void)n_in; (void)out_size; (void)ws_size;
    const float* x   = (const float*)d_in[0];
    const float* wts = (const float*)d_in[1];
    float* out = (float*)d_out;
    char* wsb = (char*)d_ws;
    float* part          = (float*)wsb;                        // 360 floats
    float* scl           = (float*)(wsb + 2048);               // 1 float
    signed char* wsum8   = (signed char*)(wsb + 4096);         // 576 KB
    unsigned char* signs = (unsigned char*)(wsb + (size_t)(1u << 20)); // 360 KB bitmap
    signed char* xq8     = (signed char*)(wsb + (size_t)(2u << 20));   // ~8.9 MB

    hipLaunchKernelGGL(k_abs_partial, dim3(NBASES * 72), dim3(256), 0, stream,
                       wts, part, signs);
    hipLaunchKernelGGL(k_prep, dim3(OC + NB * HH), dim3(256), 0, stream,
                       signs, part, wsum8, scl, x, xq8);
    hipLaunchKernelGGL(k_conv, dim3((NB * HH * WW / 128) * (OC / 128)), dim3(256), 0, stream,
                       xq8, wsum8, scl, out);
}